// Round 9
// baseline (118.507 us; speedup 1.0000x reference)
//
#include <hip/hip_runtime.h>
#include <math.h>

#define M_ROWS 8192   // B*S
#define KDIM   8192   // V
#define NDIM   512    // D
#define DH     256    // D per gather pass (WT half = 8192*256*2B = 4 MB, L2-sized)
#define RCAP   512    // list slots per row (mean nnz 82, sigma 9 -> 47-sigma)

typedef float    f32x4  __attribute__((ext_vector_type(4)));
typedef unsigned u32x2  __attribute__((ext_vector_type(2)));
typedef unsigned u32x4  __attribute__((ext_vector_type(4)));
typedef __bf16   bf16x8 __attribute__((ext_vector_type(8)));

// d_ws: [0,4M) WTh0 bf16[8192][256] | [4M,8M) WTh1 | [8M,24M) glist u32[8192][512]
//       [24M,+32K) counts u32[8192]
#define WS_GLIST  (8u  * 1024 * 1024)
#define WS_COUNT  (24u * 1024 * 1024)

// ---------------------------------------------------------------------------
// K2 (launched FIRST): pure scan+compact at HBM rate. One wave per row,
// 4-deep rotating prefetch, nontemporal A (pure stream, never reused).
// Packs (bf16(val) | v) into 4 B. Overflow -> sentinel count (exact fallback
// in gather kernel).
__global__ __launch_bounds__(256)
void scan_compact(const float* __restrict__ A, unsigned* __restrict__ glist,
                  unsigned* __restrict__ counts) {
  const int lane = threadIdx.x & 63;
  const int m    = blockIdx.x * 4 + (threadIdx.x >> 6);
  const float* arow = A + (size_t)m * KDIM;
  unsigned* rl = glist + (size_t)m * RCAP;

  const unsigned long long ltmask = (1ull << lane) - 1ull;
  unsigned cur = 0;
  bool ovf = false;

  f32x4 bufs[4];
  #pragma unroll
  for (int p = 0; p < 4; ++p)
    bufs[p] = __builtin_nontemporal_load((const f32x4*)(arow + p * 256 + lane * 4));

  #pragma unroll 4
  for (int pos = 0; pos < 32; ++pos) {
    f32x4 av = bufs[pos & 3];
    if (pos + 4 < 32)
      bufs[pos & 3] = __builtin_nontemporal_load(
          (const f32x4*)(arow + (pos + 4) * 256 + lane * 4));
    #pragma unroll
    for (int j = 0; j < 4; ++j) {
      unsigned long long msk = __ballot(av[j] != 0.0f);
      if (msk == 0) continue;
      unsigned cnt = (unsigned)__popcll(msk);
      if (cur + cnt <= RCAP) {
        if (av[j] != 0.0f) {
          unsigned pre = (unsigned)__popcll(msk & ltmask);
          unsigned fb  = (__float_as_uint(av[j]) + 0x8000u) & 0xFFFF0000u;
          rl[cur + pre] = fb | (unsigned)(pos * 256 + lane * 4 + j);
        }
        cur += cnt;
      } else {
        ovf = true;   // statistically unreachable at ~1% density
      }
    }
  }
  if (lane == 0) counts[m] = ovf ? 0xFFFFFFFFu : cur;
}

// ---------------------------------------------------------------------------
// K1 (launched SECOND, after the A-stream is done, so WT stays cache-hot):
// W [512,8192] f32 -> two half-matrices WTh[p] = bf16[8192][256].
__global__ __launch_bounds__(256)
void transpose_w(const float* __restrict__ W, __bf16* __restrict__ WTbase) {
  __shared__ float tile[64][65];
  const int t  = threadIdx.x;
  const int v0 = (blockIdx.x & 127) << 6;
  const int d0 = (blockIdx.x >> 7) << 6;
  #pragma unroll
  for (int i = 0; i < 4; ++i) {
    int idx = i * 256 + t;
    int r = idx >> 4;
    int c = (idx & 15) << 2;
    f32x4 val = *(const f32x4*)(W + (size_t)(d0 + r) * KDIM + v0 + c);
    tile[r][c + 0] = val.x; tile[r][c + 1] = val.y;
    tile[r][c + 2] = val.z; tile[r][c + 3] = val.w;
  }
  __syncthreads();
  const int half = d0 >> 8;                      // d-tile entirely in one half
  __bf16* dst = WTbase + (size_t)half * (KDIM * DH);
  #pragma unroll
  for (int i = 0; i < 2; ++i) {
    int idx = i * 256 + t;
    int vr = idx >> 3;
    int d8 = (idx & 7) << 3;
    bf16x8 u;
    #pragma unroll
    for (int j = 0; j < 8; ++j) u[j] = (__bf16)tile[d8 + j][vr];
    *(bf16x8*)(dst + (size_t)(v0 + vr) * DH + ((d0 + d8) & 255)) = u;
  }
}

// ---------------------------------------------------------------------------
// K3 (two launches): gather one 4 MB WT-half (L2-resident) + FMA + tanh.
// One wave per row; 8-deep gather pipeline; list entries broadcast via one
// coalesced load + width-8 shfl. C-stores and list-reads nontemporal so the
// WT-half owns the L2. Sentinel count -> exact re-scan of the A row.
__global__ __launch_bounds__(256)
void gather_half(const float* __restrict__ A, const __bf16* __restrict__ WTh,
                 const unsigned* __restrict__ glist,
                 const unsigned* __restrict__ counts,
                 float* __restrict__ C, int doff) {
  const int lane = threadIdx.x & 63;
  const int m    = blockIdx.x * 4 + (threadIdx.x >> 6);
  const char* wtb = (const char*)WTh;            // rows of DH*2 = 512 B
  const unsigned* rl = glist + (size_t)m * RCAP;

  float a0 = 0.f, a1 = 0.f, a2 = 0.f, a3 = 0.f;

#define FMA4(f, q)                                                          \
  {                                                                         \
    a0 = fmaf(f, __uint_as_float((q).x << 16), a0);                         \
    a1 = fmaf(f, __uint_as_float((q).x & 0xffff0000u), a1);                 \
    a2 = fmaf(f, __uint_as_float((q).y << 16), a2);                         \
    a3 = fmaf(f, __uint_as_float((q).y & 0xffff0000u), a3);                 \
  }

  const unsigned n = counts[m];
  if (n == 0xFFFFFFFFu) {
    // exact fallback (never taken at ~1% density): re-scan the row
    const float* arow = A + (size_t)m * KDIM;
    for (int it = 0; it < KDIM / 256; ++it) {
      f32x4 av = *(const f32x4*)(arow + it * 256 + lane * 4);
      #pragma unroll
      for (int j = 0; j < 4; ++j) {
        unsigned long long msk = __ballot(av[j] != 0.0f);
        while (msk) {
          int s = __builtin_ctzll(msk); msk &= msk - 1;
          float f = __shfl(av[j], s, 64);
          int v = it * 256 + s * 4 + j;
          u32x2 q = *(const u32x2*)(wtb + (size_t)v * (DH * 2) + lane * 8);
          FMA4(f, q);
        }
      }
    }
  } else if (n > 0) {
    const int ni = (int)n;
    int i0 = lane & 7;
    unsigned pr = (i0 < ni) ? __builtin_nontemporal_load(rl + i0) : 0u;
    for (int g = 0; g < ni; g += 8) {
      unsigned pk[8];
      #pragma unroll
      for (int k = 0; k < 8; ++k) {
        unsigned b = __shfl(pr, k, 8);
        pk[k] = (g + k < ni) ? b : 0u;           // pad: f=0,v=0 -> adds 0
      }
      u32x2 qv[8];
      #pragma unroll
      for (int k = 0; k < 8; ++k)
        qv[k] = *(const u32x2*)(wtb + (size_t)(pk[k] & 8191u) * (DH * 2) + lane * 8);
      int gn = g + 8 + (lane & 7);
      if (g + 8 < ni)
        pr = (gn < ni) ? __builtin_nontemporal_load(rl + gn) : 0u;
      #pragma unroll
      for (int k = 0; k < 8; ++k) {
        float f = __uint_as_float(pk[k] & 0xFFFF0000u);
        FMA4(f, qv[k]);
      }
    }
  }

  float* crow = C + (size_t)m * NDIM + doff + lane * 4;
  f32x4 o = {tanhf(a0), tanhf(a1), tanhf(a2), tanhf(a3)};
  __builtin_nontemporal_store(o, (f32x4*)crow);
#undef FMA4
}

// ---------------------------------------------------------------------------
extern "C" void kernel_launch(void* const* d_in, const int* in_sizes, int n_in,
                              void* d_out, int out_size, void* d_ws, size_t ws_size,
                              hipStream_t stream) {
  const float* x = (const float*)d_in[0];  // [8192, 8192] f32
  const float* W = (const float*)d_in[1];  // [512, 8192]  f32
  float* out = (float*)d_out;              // [8192, 512]  f32
  char* ws = (char*)d_ws;
  __bf16*   WT = (__bf16*)ws;                       // two 4 MB halves
  unsigned* gl = (unsigned*)(ws + WS_GLIST);
  unsigned* ct = (unsigned*)(ws + WS_COUNT);

  scan_compact<<<dim3(M_ROWS / 4), dim3(256), 0, stream>>>(x, gl, ct);
  transpose_w <<<dim3(1024),       dim3(256), 0, stream>>>(W, WT);
  gather_half <<<dim3(M_ROWS / 4), dim3(256), 0, stream>>>(x, WT,                    gl, ct, out, 0);
  gather_half <<<dim3(M_ROWS / 4), dim3(256), 0, stream>>>(x, WT + (size_t)KDIM * DH, gl, ct, out, DH);
}